// Round 3
// baseline (3470.078 us; speedup 1.0000x reference)
//
#include <hip/hip_runtime.h>

#define NN 100000
#define NE 600000
#define FD 128   // feature dim of h (in & hidden)

// ---------------- degree ----------------
__global__ __launch_bounds__(256) void deg_kernel(const int* __restrict__ dst,
                                                  float* __restrict__ deg, int E) {
    int t = blockIdx.x * 256 + threadIdx.x;
    if (t < E) atomicAdd(&deg[dst[t]], 1.0f);
}

__global__ __launch_bounds__(256) void invdeg_kernel(float* __restrict__ deg, int N) {
    int t = blockIdx.x * 256 + threadIdx.x;
    if (t < N) deg[t] = 1.0f / fmaxf(deg[t], 1.0f);
}

// ---------------- scatter: agg[dst] += h[src] ----------------
// one thread per (edge, 4-feature group); 2 edges per wave, coalesced 512B rows
__global__ __launch_bounds__(256) void scatter_kernel(const float* __restrict__ h,
                                                      const int* __restrict__ src,
                                                      const int* __restrict__ dst,
                                                      float* __restrict__ agg, int E) {
    int t  = blockIdx.x * 256 + threadIdx.x;
    int e  = t >> 5;
    int f4 = (t & 31) * 4;
    if (e < E) {
        int s = src[e], d = dst[e];
        float4 v = *reinterpret_cast<const float4*>(h + (size_t)s * FD + f4);
        float* a = agg + (size_t)d * FD + f4;
        atomicAdd(a + 0, v.x);
        atomicAdd(a + 1, v.y);
        atomicAdd(a + 2, v.z);
        atomicAdd(a + 3, v.w);
    }
}

// ---------------- fused SAGE GEMM ----------------
// out[n, 0:BN] = h[n,:] @ Wself^T + (agg[n,:]*invdeg[n]) @ Wneigh^T + bias  (+ReLU)
// Combined K = 256 (first 128 = h/Wself, last 128 = agg/Wneigh).
// BM=64, BN=dout, BK=32, 256 threads; thread computes 4 rows x (BN/16) cols.
template <int BN, bool RELU>
__global__ __launch_bounds__(256) void sage_gemm(const float* __restrict__ h,
                                                 const float* __restrict__ agg,
                                                 const float* __restrict__ invdeg,
                                                 const float* __restrict__ Wself,
                                                 const float* __restrict__ Wneigh,
                                                 const float* __restrict__ bias,
                                                 float* __restrict__ out, int N) {
    constexpr int BM = 64, BK = 32;
    constexpr int TC = BN / 16;               // cols per thread: 8 (BN=128) or 4 (BN=64)
    __shared__ float As[BK][BM + 4];          // stride 68 floats = 272B (16B aligned)
    __shared__ float Bs[BK][BN + 4];          // stride 132/68 floats (16B aligned)

    const int t  = threadIdx.x;
    const int n0 = blockIdx.x * BM;
    const int tr = t / 16;                    // 0..15 row group
    const int tc = t % 16;                    // 0..15 col group

    float acc[4][TC];
#pragma unroll
    for (int i = 0; i < 4; ++i)
#pragma unroll
        for (int j = 0; j < TC; ++j) acc[i][j] = 0.0f;

#pragma unroll 1
    for (int kc = 0; kc < 8; ++kc) {          // 8 chunks of BK=32 over K=256
        // ---- stage A (transposed, k-major) ----
#pragma unroll
        for (int p = 0; p < 2; ++p) {
            int r  = (t / 8) + p * 32;        // row in tile
            int kq = (t % 8) * 4;             // k offset within chunk
            int n  = n0 + r;
            int k  = kc * 32 + kq;            // combined k (chunk never straddles 128)
            float4 v = make_float4(0.f, 0.f, 0.f, 0.f);
            if (n < N) {
                if (k < 128) {
                    v = *reinterpret_cast<const float4*>(h + (size_t)n * FD + k);
                } else {
                    v = *reinterpret_cast<const float4*>(agg + (size_t)n * FD + (k - 128));
                    float iv = invdeg[n];
                    v.x *= iv; v.y *= iv; v.z *= iv; v.w *= iv;
                }
            }
            As[kq + 0][r] = v.x;
            As[kq + 1][r] = v.y;
            As[kq + 2][r] = v.z;
            As[kq + 3][r] = v.w;
        }
        // ---- stage B (transposed, k-major): B[k][j] = W[j][k] ----
#pragma unroll
        for (int p = 0; p < BN / 32; ++p) {
            int j  = (t / 8) + p * 32;
            int kq = (t % 8) * 4;
            int k  = kc * 32 + kq;
            const float* W = (k < 128) ? Wself : Wneigh;
            int kw = (k < 128) ? k : k - 128;
            float4 v = *reinterpret_cast<const float4*>(W + (size_t)j * 128 + kw);
            Bs[kq + 0][j] = v.x;
            Bs[kq + 1][j] = v.y;
            Bs[kq + 2][j] = v.z;
            Bs[kq + 3][j] = v.w;
        }
        __syncthreads();

#pragma unroll
        for (int kk = 0; kk < BK; ++kk) {
            float4 a = *reinterpret_cast<const float4*>(&As[kk][tr * 4]);
            float av[4] = {a.x, a.y, a.z, a.w};
            float bv[TC];
#pragma unroll
            for (int q = 0; q < TC / 4; ++q) {
                float4 b = *reinterpret_cast<const float4*>(&Bs[kk][tc * TC + q * 4]);
                bv[q * 4 + 0] = b.x; bv[q * 4 + 1] = b.y;
                bv[q * 4 + 2] = b.z; bv[q * 4 + 3] = b.w;
            }
#pragma unroll
            for (int i = 0; i < 4; ++i)
#pragma unroll
                for (int j = 0; j < TC; ++j) acc[i][j] += av[i] * bv[j];
        }
        __syncthreads();
    }

    // ---- epilogue: bias (+ReLU), float4 stores ----
#pragma unroll
    for (int i = 0; i < 4; ++i) {
        int n = n0 + tr * 4 + i;
        if (n < N) {
#pragma unroll
            for (int q = 0; q < TC / 4; ++q) {
                int j = tc * TC + q * 4;
                float4 o;
                o.x = acc[i][q * 4 + 0] + bias[j + 0];
                o.y = acc[i][q * 4 + 1] + bias[j + 1];
                o.z = acc[i][q * 4 + 2] + bias[j + 2];
                o.w = acc[i][q * 4 + 3] + bias[j + 3];
                if (RELU) {
                    o.x = fmaxf(o.x, 0.f); o.y = fmaxf(o.y, 0.f);
                    o.z = fmaxf(o.z, 0.f); o.w = fmaxf(o.w, 0.f);
                }
                *reinterpret_cast<float4*>(out + (size_t)n * BN + j) = o;
            }
        }
    }
}

extern "C" void kernel_launch(void* const* d_in, const int* in_sizes, int n_in,
                              void* d_out, int out_size, void* d_ws, size_t ws_size,
                              hipStream_t stream) {
    const float* x        = (const float*)d_in[0];
    const int*   edge_src = (const int*)d_in[1];
    const int*   edge_dst = (const int*)d_in[2];
    const float* Ws1 = (const float*)d_in[3];
    const float* Wn1 = (const float*)d_in[4];
    const float* b1  = (const float*)d_in[5];
    const float* Ws2 = (const float*)d_in[6];
    const float* Wn2 = (const float*)d_in[7];
    const float* b2  = (const float*)d_in[8];
    const float* Ws3 = (const float*)d_in[9];
    const float* Wn3 = (const float*)d_in[10];
    const float* b3  = (const float*)d_in[11];
    float* out = (float*)d_out;

    // workspace: h_buf [NN*128] | agg [NN*128] | invdeg [NN]
    float* h_buf = (float*)d_ws;
    float* agg   = h_buf + (size_t)NN * FD;
    float* ideg  = agg + (size_t)NN * FD;

    const size_t aggBytes = (size_t)NN * FD * sizeof(float);

    const int degGrid  = (NE + 255) / 256;
    const int invGrid  = (NN + 255) / 256;
    const int scatGrid = (NE * 32) / 256;     // 75000
    const int gemmGrid = (NN + 63) / 64;      // 1563

    // degree (edge structure constant across layers)
    hipMemsetAsync(ideg, 0, (size_t)NN * sizeof(float), stream);
    deg_kernel<<<degGrid, 256, 0, stream>>>(edge_dst, ideg, NE);
    invdeg_kernel<<<invGrid, 256, 0, stream>>>(ideg, NN);

    // ---- layer 1: x -> h_buf ----
    hipMemsetAsync(agg, 0, aggBytes, stream);
    scatter_kernel<<<scatGrid, 256, 0, stream>>>(x, edge_src, edge_dst, agg, NE);
    sage_gemm<128, true><<<gemmGrid, 256, 0, stream>>>(x, agg, ideg, Ws1, Wn1, b1, h_buf, NN);

    // ---- layer 2: h_buf -> h_buf (in-place safe: BN covers all cols) ----
    hipMemsetAsync(agg, 0, aggBytes, stream);
    scatter_kernel<<<scatGrid, 256, 0, stream>>>(h_buf, edge_src, edge_dst, agg, NE);
    sage_gemm<128, true><<<gemmGrid, 256, 0, stream>>>(h_buf, agg, ideg, Ws2, Wn2, b2, h_buf, NN);

    // ---- layer 3: h_buf -> out (dout=64, no ReLU) ----
    hipMemsetAsync(agg, 0, aggBytes, stream);
    scatter_kernel<<<scatGrid, 256, 0, stream>>>(h_buf, edge_src, edge_dst, agg, NE);
    sage_gemm<64, false><<<gemmGrid, 256, 0, stream>>>(h_buf, agg, ideg, Ws3, Wn3, b3, out, NN);
}

// Round 6
// 645.181 us; speedup vs baseline: 5.3785x; 5.3785x over previous
//
#include <hip/hip_runtime.h>

#define NN 100000
#define NE 600000
#define FD 128                       // feature dim of h (in & hidden)
#define NB ((NN + 255) / 256)        // 391 scan blocks

// ================= CSR build (by destination) =================
// cnt/cursor buffer is reused: hist writes cnt; scans read cnt; then the
// same buffer receives a copy of row_ptr and becomes the fill cursor.

__global__ __launch_bounds__(256) void hist_kernel(const int* __restrict__ dst,
                                                   int* __restrict__ cnt, int E) {
    int e = blockIdx.x * 256 + threadIdx.x;
    if (e < E) atomicAdd(&cnt[dst[e]], 1);
}

__global__ __launch_bounds__(256) void scan_blocks(const int* __restrict__ cnt,
                                                   int* __restrict__ bsum) {
    __shared__ int s[256];
    int i = blockIdx.x * 256 + threadIdx.x;
    int t = threadIdx.x;
    s[t] = (i < NN) ? cnt[i] : 0;
    __syncthreads();
    for (int off = 128; off > 0; off >>= 1) {
        if (t < off) s[t] += s[t + off];
        __syncthreads();
    }
    if (t == 0) bsum[blockIdx.x] = s[0];
}

__global__ __launch_bounds__(512) void scan_top(int* __restrict__ bsum,
                                                int* __restrict__ row_ptr) {
    __shared__ int s[512];
    int t = threadIdx.x;
    int v = (t < NB) ? bsum[t] : 0;
    s[t] = v;
    __syncthreads();
    for (int off = 1; off < 512; off <<= 1) {
        int x = (t >= off) ? s[t - off] : 0;
        __syncthreads();
        s[t] += x;
        __syncthreads();
    }
    if (t < NB) bsum[t] = s[t] - v;          // exclusive block offsets
    if (t == 0) row_ptr[NN] = NE;            // total edges (constant)
}

__global__ __launch_bounds__(256) void scan_write(const int* __restrict__ cnt,
                                                  const int* __restrict__ bofs,
                                                  int* __restrict__ row_ptr) {
    __shared__ int s[256];
    int i = blockIdx.x * 256 + threadIdx.x;
    int t = threadIdx.x;
    int v = (i < NN) ? cnt[i] : 0;
    s[t] = v;
    __syncthreads();
    for (int off = 1; off < 256; off <<= 1) {
        int x = (t >= off) ? s[t - off] : 0;
        __syncthreads();
        s[t] += x;
        __syncthreads();
    }
    if (i < NN) row_ptr[i] = s[t] - v + bofs[blockIdx.x];
}

__global__ __launch_bounds__(256) void fill_kernel(const int* __restrict__ src,
                                                   const int* __restrict__ dst,
                                                   int* __restrict__ cursor,
                                                   int* __restrict__ col, int E) {
    int e = blockIdx.x * 256 + threadIdx.x;
    if (e < E) {
        int p = atomicAdd(&cursor[dst[e]], 1);
        col[p] = src[e];
    }
}

// ================= gather-mean aggregation =================
// one wave per dst node; lane l holds features [2l, 2l+1]; loop in-edges,
// accumulate in registers, single mean-scaled write. No atomics, no memset.
__global__ __launch_bounds__(256) void agg_kernel(const float* __restrict__ h,
                                                  const int* __restrict__ rp,
                                                  const int* __restrict__ col,
                                                  float* __restrict__ agg) {
    int w    = (blockIdx.x * 256 + threadIdx.x) >> 6;   // node = global wave id
    int lane = threadIdx.x & 63;
    if (w >= NN) return;
    int beg = rp[w], end = rp[w + 1];
    float2 acc = make_float2(0.f, 0.f);
    for (int e = beg; e < end; ++e) {
        int s = col[e];                                  // wave-uniform load
        float2 v = *reinterpret_cast<const float2*>(h + (size_t)s * FD + lane * 2);
        acc.x += v.x;
        acc.y += v.y;
    }
    float inv = 1.0f / fmaxf((float)(end - beg), 1.0f);
    acc.x *= inv;
    acc.y *= inv;
    *reinterpret_cast<float2*>(agg + (size_t)w * FD + lane * 2) = acc;
}

// ================= fused SAGE GEMM =================
// out[n,0:BN] = h[n,:] @ Wself^T + agg[n,:] @ Wneigh^T + bias (+ReLU)
// agg is already mean-scaled. Combined K=256. BM=64, BK=32, 256 threads.
template <int BN, bool RELU>
__global__ __launch_bounds__(256) void sage_gemm(const float* __restrict__ h,
                                                 const float* __restrict__ agg,
                                                 const float* __restrict__ Wself,
                                                 const float* __restrict__ Wneigh,
                                                 const float* __restrict__ bias,
                                                 float* __restrict__ out, int N) {
    constexpr int BM = 64, BK = 32;
    constexpr int TC = BN / 16;               // cols per thread: 8 or 4
    __shared__ float As[BK][BM + 4];
    __shared__ float Bs[BK][BN + 4];

    const int t  = threadIdx.x;
    const int n0 = blockIdx.x * BM;
    const int tr = t / 16;
    const int tc = t % 16;

    float acc[4][TC];
#pragma unroll
    for (int i = 0; i < 4; ++i)
#pragma unroll
        for (int j = 0; j < TC; ++j) acc[i][j] = 0.0f;

#pragma unroll 1
    for (int kc = 0; kc < 8; ++kc) {
        // ---- stage A (k-major transpose) ----
#pragma unroll
        for (int p = 0; p < 2; ++p) {
            int r  = (t / 8) + p * 32;
            int kq = (t % 8) * 4;
            int n  = n0 + r;
            int k  = kc * 32 + kq;
            float4 v = make_float4(0.f, 0.f, 0.f, 0.f);
            if (n < N) {
                const float* srcp = (k < 128) ? (h + (size_t)n * FD + k)
                                              : (agg + (size_t)n * FD + (k - 128));
                v = *reinterpret_cast<const float4*>(srcp);
            }
            As[kq + 0][r] = v.x;
            As[kq + 1][r] = v.y;
            As[kq + 2][r] = v.z;
            As[kq + 3][r] = v.w;
        }
        // ---- stage B: B[k][j] = W[j][k] ----
#pragma unroll
        for (int p = 0; p < BN / 32; ++p) {
            int j  = (t / 8) + p * 32;
            int kq = (t % 8) * 4;
            int k  = kc * 32 + kq;
            const float* W = (k < 128) ? Wself : Wneigh;
            int kw = (k < 128) ? k : k - 128;
            float4 v = *reinterpret_cast<const float4*>(W + (size_t)j * 128 + kw);
            Bs[kq + 0][j] = v.x;
            Bs[kq + 1][j] = v.y;
            Bs[kq + 2][j] = v.z;
            Bs[kq + 3][j] = v.w;
        }
        __syncthreads();

#pragma unroll
        for (int kk = 0; kk < BK; ++kk) {
            float4 a = *reinterpret_cast<const float4*>(&As[kk][tr * 4]);
            float av[4] = {a.x, a.y, a.z, a.w};
            float bv[TC];
#pragma unroll
            for (int q = 0; q < TC / 4; ++q) {
                float4 b = *reinterpret_cast<const float4*>(&Bs[kk][tc * TC + q * 4]);
                bv[q * 4 + 0] = b.x; bv[q * 4 + 1] = b.y;
                bv[q * 4 + 2] = b.z; bv[q * 4 + 3] = b.w;
            }
#pragma unroll
            for (int i = 0; i < 4; ++i)
#pragma unroll
                for (int j = 0; j < TC; ++j) acc[i][j] += av[i] * bv[j];
        }
        __syncthreads();
    }

#pragma unroll
    for (int i = 0; i < 4; ++i) {
        int n = n0 + tr * 4 + i;
        if (n < N) {
#pragma unroll
            for (int q = 0; q < TC / 4; ++q) {
                int j = tc * TC + q * 4;
                float4 o;
                o.x = acc[i][q * 4 + 0] + bias[j + 0];
                o.y = acc[i][q * 4 + 1] + bias[j + 1];
                o.z = acc[i][q * 4 + 2] + bias[j + 2];
                o.w = acc[i][q * 4 + 3] + bias[j + 3];
                if (RELU) {
                    o.x = fmaxf(o.x, 0.f); o.y = fmaxf(o.y, 0.f);
                    o.z = fmaxf(o.z, 0.f); o.w = fmaxf(o.w, 0.f);
                }
                *reinterpret_cast<float4*>(out + (size_t)n * BN + j) = o;
            }
        }
    }
}

extern "C" void kernel_launch(void* const* d_in, const int* in_sizes, int n_in,
                              void* d_out, int out_size, void* d_ws, size_t ws_size,
                              hipStream_t stream) {
    const float* x        = (const float*)d_in[0];
    const int*   edge_src = (const int*)d_in[1];
    const int*   edge_dst = (const int*)d_in[2];
    const float* Ws1 = (const float*)d_in[3];
    const float* Wn1 = (const float*)d_in[4];
    const float* b1  = (const float*)d_in[5];
    const float* Ws2 = (const float*)d_in[6];
    const float* Wn2 = (const float*)d_in[7];
    const float* b2  = (const float*)d_in[8];
    const float* Ws3 = (const float*)d_in[9];
    const float* Wn3 = (const float*)d_in[10];
    const float* b3  = (const float*)d_in[11];
    float* out = (float*)d_out;

    // ---- memory plan (d_ws usage == proven-safe 102.8 MB footprint) ----
    // d_ws : h_buf [NN*FD] | agg [NN*FD] | cursor [NN ints]
    // d_out: col_src [NE ints] | row_ptr [NN+1 ints]   (d_out = 25.6 MB; CSR
    //        reads all complete before the final GEMM overwrites d_out)
    // bsum aliases the head of agg (dead until first agg_kernel, which runs
    //        after CSR build completes).
    float* h_buf   = (float*)d_ws;
    float* agg     = h_buf + (size_t)NN * FD;            // +51.2 MB
    int*   cursor  = (int*)(agg + (size_t)NN * FD);      // NN ints (also cnt)
    int*   bsum    = (int*)agg;                          // NB ints, dead early
    int*   col_src = (int*)d_out;                        // NE ints
    int*   row_ptr = col_src + NE;                       // NN+1 ints

    const int edgeGrid = (NE + 255) / 256;               // 2344
    const int aggGrid  = NN / 4;                         // 25000 (4 waves/block)
    const int gemmGrid = (NN + 63) / 64;                 // 1563

    // ---- CSR build (once; edge structure shared across layers) ----
    hipMemsetAsync(cursor, 0, (size_t)NN * sizeof(int), stream);     // cnt = 0
    hist_kernel<<<edgeGrid, 256, 0, stream>>>(edge_dst, cursor, NE); // cnt
    scan_blocks<<<NB, 256, 0, stream>>>(cursor, bsum);
    scan_top<<<1, 512, 0, stream>>>(bsum, row_ptr);
    scan_write<<<NB, 256, 0, stream>>>(cursor, bsum, row_ptr);
    hipMemcpyAsync(cursor, row_ptr, (size_t)NN * sizeof(int),
                   hipMemcpyDeviceToDevice, stream);                 // cursor
    fill_kernel<<<edgeGrid, 256, 0, stream>>>(edge_src, edge_dst, cursor,
                                              col_src, NE);

    // ---- layer 1: x -> h_buf ----
    agg_kernel<<<aggGrid, 256, 0, stream>>>(x, row_ptr, col_src, agg);
    sage_gemm<128, true><<<gemmGrid, 256, 0, stream>>>(x, agg, Ws1, Wn1, b1, h_buf, NN);

    // ---- layer 2: h_buf -> h_buf (in-place safe: each row read only by its writer block) ----
    agg_kernel<<<aggGrid, 256, 0, stream>>>(h_buf, row_ptr, col_src, agg);
    sage_gemm<128, true><<<gemmGrid, 256, 0, stream>>>(h_buf, agg, Ws2, Wn2, b2, h_buf, NN);

    // ---- layer 3: h_buf -> out (dout=64, no ReLU; overwrites CSR in d_out) ----
    agg_kernel<<<aggGrid, 256, 0, stream>>>(h_buf, row_ptr, col_src, agg);
    sage_gemm<64, false><<<gemmGrid, 256, 0, stream>>>(h_buf, agg, Ws3, Wn3, b3, out, NN);
}

// Round 8
// 504.971 us; speedup vs baseline: 6.8718x; 1.2777x over previous
//
#include <hip/hip_runtime.h>

#define NN 100000
#define NE 600000
#define FD 128                       // feature dim of h (in & hidden)
#define NB ((NN + 255) / 256)        // 391 scan blocks

typedef __attribute__((ext_vector_type(8))) short bf16x8;
typedef __attribute__((ext_vector_type(4))) float f32x4;

__device__ __forceinline__ unsigned short f2bf(float x) {
    unsigned int u = __float_as_uint(x);
    u += 0x7FFFu + ((u >> 16) & 1u);          // RNE
    return (unsigned short)(u >> 16);
}

// ================= CSR build (by destination) =================
__global__ __launch_bounds__(256) void hist_kernel(const int* __restrict__ dst,
                                                   int* __restrict__ cnt, int E) {
    int e = blockIdx.x * 256 + threadIdx.x;
    if (e < E) atomicAdd(&cnt[dst[e]], 1);
}

__global__ __launch_bounds__(256) void scan_blocks(const int* __restrict__ cnt,
                                                   int* __restrict__ bsum) {
    __shared__ int s[256];
    int i = blockIdx.x * 256 + threadIdx.x;
    int t = threadIdx.x;
    s[t] = (i < NN) ? cnt[i] : 0;
    __syncthreads();
    for (int off = 128; off > 0; off >>= 1) {
        if (t < off) s[t] += s[t + off];
        __syncthreads();
    }
    if (t == 0) bsum[blockIdx.x] = s[0];
}

__global__ __launch_bounds__(512) void scan_top(int* __restrict__ bsum,
                                                int* __restrict__ row_ptr) {
    __shared__ int s[512];
    int t = threadIdx.x;
    int v = (t < NB) ? bsum[t] : 0;
    s[t] = v;
    __syncthreads();
    for (int off = 1; off < 512; off <<= 1) {
        int x = (t >= off) ? s[t - off] : 0;
        __syncthreads();
        s[t] += x;
        __syncthreads();
    }
    if (t < NB) bsum[t] = s[t] - v;          // exclusive block offsets
    if (t == 0) row_ptr[NN] = NE;
}

__global__ __launch_bounds__(256) void scan_write(const int* __restrict__ cnt,
                                                  const int* __restrict__ bofs,
                                                  int* __restrict__ row_ptr) {
    __shared__ int s[256];
    int i = blockIdx.x * 256 + threadIdx.x;
    int t = threadIdx.x;
    int v = (i < NN) ? cnt[i] : 0;
    s[t] = v;
    __syncthreads();
    for (int off = 1; off < 256; off <<= 1) {
        int x = (t >= off) ? s[t - off] : 0;
        __syncthreads();
        s[t] += x;
        __syncthreads();
    }
    if (i < NN) row_ptr[i] = s[t] - v + bofs[blockIdx.x];
}

__global__ __launch_bounds__(256) void fill_kernel(const int* __restrict__ src,
                                                   const int* __restrict__ dst,
                                                   int* __restrict__ cursor,
                                                   int* __restrict__ col, int E) {
    int e = blockIdx.x * 256 + threadIdx.x;
    if (e < E) {
        int p = atomicAdd(&cursor[dst[e]], 1);
        col[p] = src[e];
    }
}

// ================= f32 -> bf16 conversion (x once per call) =================
__global__ __launch_bounds__(256) void cvt_kernel(const float* __restrict__ x,
                                                  unsigned short* __restrict__ xb,
                                                  int n4) {
    int i = blockIdx.x * 256 + threadIdx.x;
    if (i < n4) {
        float4 v = reinterpret_cast<const float4*>(x)[i];
        uint2 o;
        o.x = (unsigned)f2bf(v.x) | ((unsigned)f2bf(v.y) << 16);
        o.y = (unsigned)f2bf(v.z) | ((unsigned)f2bf(v.w) << 16);
        reinterpret_cast<uint2*>(xb)[i] = o;
    }
}

// ================= gather-mean aggregation (bf16 in, bf16 out, f32 accum) ===
// one wave per dst node; lane l holds features [2l, 2l+1] (4B packed bf16x2)
__global__ __launch_bounds__(256) void agg_kernel(const unsigned short* __restrict__ h,
                                                  const int* __restrict__ rp,
                                                  const int* __restrict__ col,
                                                  unsigned short* __restrict__ agg) {
    int w    = (blockIdx.x * 256 + threadIdx.x) >> 6;
    int lane = threadIdx.x & 63;
    if (w >= NN) return;
    int beg = rp[w], end = rp[w + 1];
    float ax = 0.f, ay = 0.f;
    for (int e = beg; e < end; ++e) {
        int s = col[e];                                  // wave-uniform
        unsigned v = *reinterpret_cast<const unsigned*>(h + (size_t)s * FD + lane * 2);
        ax += __uint_as_float(v << 16);
        ay += __uint_as_float(v & 0xFFFF0000u);
    }
    float inv = 1.0f / fmaxf((float)(end - beg), 1.0f);
    ax *= inv;
    ay *= inv;
    *reinterpret_cast<unsigned*>(agg + (size_t)w * FD + lane * 2) =
        (unsigned)f2bf(ax) | ((unsigned)f2bf(ay) << 16);
}

// ================= MFMA SAGE GEMM =================
// out[n, jbase:jbase+64] = [h|agg](n,:) @ [Wself|Wneigh]^T + bias  (+ReLU)
// Tile 64 rows x 64 cols, K=256. 4 waves; wave w owns rows 16w..16w+15,
// 4 col-frags of 16. LDS A/B tiles [64][256] bf16, XOR-swizzled (T2):
// byte ^= (row&7)<<4 — row stride 512B would otherwise be a 32-way conflict.
// B staged from f32 weights with on-the-fly bf16 convert (weights L2-resident).
template <int NCOLS, bool RELU, bool OUTBF16>
__global__ __launch_bounds__(256) void mfma_gemm(const unsigned short* __restrict__ Ah,
                                                 const unsigned short* __restrict__ Ag,
                                                 const float* __restrict__ Wself,
                                                 const float* __restrict__ Wneigh,
                                                 const float* __restrict__ bias,
                                                 void* __restrict__ outp, int N) {
    __shared__ char lds[65536];                  // A: [0,32K) B: [32K,64K)
    char* Al = lds;
    char* Bl = lds + 32768;

    const int t     = threadIdx.x;
    const int n0    = blockIdx.x * 64;
    const int jbase = blockIdx.y * 64;

    // ---- stage A (h|agg rows) and B (weights, f32->bf16) ----
#pragma unroll
    for (int p = 0; p < 8; ++p) {
        int c    = t + p * 256;                  // chunk id 0..2047
        int row  = c >> 5;                       // 0..63
        int ch16 = c & 31;                       // 16B chunk within row
        int k8   = ch16 * 8;                     // k element base
        int n    = n0 + row;
        uint4 v  = make_uint4(0u, 0u, 0u, 0u);
        if (n < N) {
            const unsigned short* src = (k8 < 128)
                ? Ah + (size_t)n * FD + k8
                : Ag + (size_t)n * FD + (k8 - 128);
            v = *reinterpret_cast<const uint4*>(src);
        }
        *reinterpret_cast<uint4*>(Al + ((row * 512 + ch16 * 16) ^ ((row & 7) << 4))) = v;
    }
#pragma unroll
    for (int p = 0; p < 8; ++p) {
        int c    = t + p * 256;
        int row  = c >> 5;                       // output col within tile
        int ch16 = c & 31;
        int k8   = ch16 * 8;
        int j    = jbase + row;
        const float* src = (k8 < 128) ? (Wself + (size_t)j * 128 + k8)
                                      : (Wneigh + (size_t)j * 128 + (k8 - 128));
        float4 f0 = *reinterpret_cast<const float4*>(src);
        float4 f1 = *reinterpret_cast<const float4*>(src + 4);
        uint4 pk;
        pk.x = (unsigned)f2bf(f0.x) | ((unsigned)f2bf(f0.y) << 16);
        pk.y = (unsigned)f2bf(f0.z) | ((unsigned)f2bf(f0.w) << 16);
        pk.z = (unsigned)f2bf(f1.x) | ((unsigned)f2bf(f1.y) << 16);
        pk.w = (unsigned)f2bf(f1.z) | ((unsigned)f2bf(f1.w) << 16);
        *reinterpret_cast<uint4*>(Bl + ((row * 512 + ch16 * 16) ^ ((row & 7) << 4))) = pk;
    }
    __syncthreads();

    // ---- MFMA K-loop ----
    const int w   = t >> 6;
    const int l   = t & 63;
    const int lo4 = l & 15;
    const int hi  = l >> 4;
    const int xr  = (lo4 & 7) << 4;              // row&7 == lo4&7 for A and B

    f32x4 acc0 = {0.f, 0.f, 0.f, 0.f};
    f32x4 acc1 = {0.f, 0.f, 0.f, 0.f};
    f32x4 acc2 = {0.f, 0.f, 0.f, 0.f};
    f32x4 acc3 = {0.f, 0.f, 0.f, 0.f};

    const char* Arow = Al + (w * 16 + lo4) * 512;
#pragma unroll
    for (int ks = 0; ks < 8; ++ks) {
        int koff = (ks * 64 + hi * 16) ^ xr;
        bf16x8 a = *reinterpret_cast<const bf16x8*>(Arow + koff);
        bf16x8 b0 = *reinterpret_cast<const bf16x8*>(Bl + (0 * 16 + lo4) * 512 + koff);
        bf16x8 b1 = *reinterpret_cast<const bf16x8*>(Bl + (1 * 16 + lo4) * 512 + koff);
        bf16x8 b2 = *reinterpret_cast<const bf16x8*>(Bl + (2 * 16 + lo4) * 512 + koff);
        bf16x8 b3 = *reinterpret_cast<const bf16x8*>(Bl + (3 * 16 + lo4) * 512 + koff);
        acc0 = __builtin_amdgcn_mfma_f32_16x16x32_bf16(a, b0, acc0, 0, 0, 0);
        acc1 = __builtin_amdgcn_mfma_f32_16x16x32_bf16(a, b1, acc1, 0, 0, 0);
        acc2 = __builtin_amdgcn_mfma_f32_16x16x32_bf16(a, b2, acc2, 0, 0, 0);
        acc3 = __builtin_amdgcn_mfma_f32_16x16x32_bf16(a, b3, acc3, 0, 0, 0);
    }

    // ---- epilogue: bias (+ReLU); C/D map col=l&15, row=(l>>4)*4+reg (m89) ----
    unsigned short* hout = (unsigned short*)outp;
    float* fout = (float*)outp;
    const int rbase = n0 + w * 16 + hi * 4;
#pragma unroll
    for (int f = 0; f < 4; ++f) {
        f32x4 acc = (f == 0) ? acc0 : (f == 1) ? acc1 : (f == 2) ? acc2 : acc3;
        int col = jbase + f * 16 + lo4;
        float bv = bias[col];
#pragma unroll
        for (int r = 0; r < 4; ++r) {
            int n = rbase + r;
            if (n < N) {
                float v = acc[r] + bv;
                if (RELU) v = fmaxf(v, 0.f);
                if (OUTBF16) hout[(size_t)n * 128 + col] = f2bf(v);
                else         fout[(size_t)n * NCOLS + col] = v;
            }
        }
    }
}

extern "C" void kernel_launch(void* const* d_in, const int* in_sizes, int n_in,
                              void* d_out, int out_size, void* d_ws, size_t ws_size,
                              hipStream_t stream) {
    const float* x        = (const float*)d_in[0];
    const int*   edge_src = (const int*)d_in[1];
    const int*   edge_dst = (const int*)d_in[2];
    const float* Ws1 = (const float*)d_in[3];
    const float* Wn1 = (const float*)d_in[4];
    const float* b1  = (const float*)d_in[5];
    const float* Ws2 = (const float*)d_in[6];
    const float* Wn2 = (const float*)d_in[7];
    const float* b2  = (const float*)d_in[8];
    const float* Ws3 = (const float*)d_in[9];
    const float* Wn3 = (const float*)d_in[10];
    const float* b3  = (const float*)d_in[11];
    float* out = (float*)d_out;

    // ---- memory plan (d_ws == proven-safe 102.8 MB footprint) ----
    // d_ws : x_bf16 | h_a | h_b | agg (each NN*FD bf16 = 25.6MB) | cursor
    // d_out: col_src [NE] | row_ptr [NN+1] (CSR reads all precede final GEMM)
    // bsum aliases agg head (dead until first agg_kernel).
    unsigned short* x_bf = (unsigned short*)d_ws;
    unsigned short* h_a  = x_bf + (size_t)NN * FD;
    unsigned short* h_b  = h_a + (size_t)NN * FD;
    unsigned short* aggb = h_b + (size_t)NN * FD;
    int* cursor = (int*)(aggb + (size_t)NN * FD);
    int* bsum   = (int*)aggb;
    int* col_src = (int*)d_out;
    int* row_ptr = col_src + NE;

    const int edgeGrid = (NE + 255) / 256;
    const int aggGrid  = NN / 4;                         // 4 waves/block
    const int rowGrid  = (NN + 63) / 64;                 // 1563

    // ---- x -> bf16 ----
    cvt_kernel<<<(NN * FD / 4 + 255) / 256, 256, 0, stream>>>(x, x_bf, NN * FD / 4);

    // ---- CSR build ----
    hipMemsetAsync(cursor, 0, (size_t)NN * sizeof(int), stream);
    hist_kernel<<<edgeGrid, 256, 0, stream>>>(edge_dst, cursor, NE);
    scan_blocks<<<NB, 256, 0, stream>>>(cursor, bsum);
    scan_top<<<1, 512, 0, stream>>>(bsum, row_ptr);
    scan_write<<<NB, 256, 0, stream>>>(cursor, bsum, row_ptr);
    hipMemcpyAsync(cursor, row_ptr, (size_t)NN * sizeof(int),
                   hipMemcpyDeviceToDevice, stream);
    fill_kernel<<<edgeGrid, 256, 0, stream>>>(edge_src, edge_dst, cursor,
                                              col_src, NE);

    // ---- layer 1: x_bf -> h_a ----
    agg_kernel<<<aggGrid, 256, 0, stream>>>(x_bf, row_ptr, col_src, aggb);
    mfma_gemm<128, true, true><<<dim3(rowGrid, 2), 256, 0, stream>>>(
        x_bf, aggb, Ws1, Wn1, b1, h_a, NN);

    // ---- layer 2: h_a -> h_b ----
    agg_kernel<<<aggGrid, 256, 0, stream>>>(h_a, row_ptr, col_src, aggb);
    mfma_gemm<128, true, true><<<dim3(rowGrid, 2), 256, 0, stream>>>(
        h_a, aggb, Ws2, Wn2, b2, h_b, NN);

    // ---- layer 3: h_b -> out (f32, no ReLU; overwrites CSR in d_out) ----
    agg_kernel<<<aggGrid, 256, 0, stream>>>(h_b, row_ptr, col_src, aggb);
    mfma_gemm<64, false, false><<<dim3(rowGrid, 1), 256, 0, stream>>>(
        h_b, aggb, Ws3, Wn3, b3, out, NN);
}

// Round 10
// 399.764 us; speedup vs baseline: 8.6803x; 1.2632x over previous
//
#include <hip/hip_runtime.h>

#define NN 100000
#define NE 600000
#define FD 128                       // feature dim of h (in & hidden)
#define NB ((NN + 255) / 256)        // 391 scan blocks

typedef __attribute__((ext_vector_type(8))) short bf16x8;
typedef __attribute__((ext_vector_type(4))) float f32x4;

__device__ __forceinline__ unsigned short f2bf(float x) {
    unsigned int u = __float_as_uint(x);
    u += 0x7FFFu + ((u >> 16) & 1u);          // RNE
    return (unsigned short)(u >> 16);
}

// ================= CSR build (by destination) =================
__global__ __launch_bounds__(256) void hist_kernel(const int* __restrict__ dst,
                                                   int* __restrict__ cnt, int E) {
    int e = blockIdx.x * 256 + threadIdx.x;
    if (e < E) atomicAdd(&cnt[dst[e]], 1);
}

__global__ __launch_bounds__(256) void scan_blocks(const int* __restrict__ cnt,
                                                   int* __restrict__ bsum) {
    __shared__ int s[256];
    int i = blockIdx.x * 256 + threadIdx.x;
    int t = threadIdx.x;
    s[t] = (i < NN) ? cnt[i] : 0;
    __syncthreads();
    for (int off = 128; off > 0; off >>= 1) {
        if (t < off) s[t] += s[t + off];
        __syncthreads();
    }
    if (t == 0) bsum[blockIdx.x] = s[0];
}

__global__ __launch_bounds__(512) void scan_top(int* __restrict__ bsum,
                                                int* __restrict__ row_ptr) {
    __shared__ int s[512];
    int t = threadIdx.x;
    int v = (t < NB) ? bsum[t] : 0;
    s[t] = v;
    __syncthreads();
    for (int off = 1; off < 512; off <<= 1) {
        int x = (t >= off) ? s[t - off] : 0;
        __syncthreads();
        s[t] += x;
        __syncthreads();
    }
    if (t < NB) bsum[t] = s[t] - v;          // exclusive block offsets
    if (t == 0) row_ptr[NN] = NE;
}

__global__ __launch_bounds__(256) void scan_write(const int* __restrict__ cnt,
                                                  const int* __restrict__ bofs,
                                                  int* __restrict__ row_ptr) {
    __shared__ int s[256];
    int i = blockIdx.x * 256 + threadIdx.x;
    int t = threadIdx.x;
    int v = (i < NN) ? cnt[i] : 0;
    s[t] = v;
    __syncthreads();
    for (int off = 1; off < 256; off <<= 1) {
        int x = (t >= off) ? s[t - off] : 0;
        __syncthreads();
        s[t] += x;
        __syncthreads();
    }
    if (i < NN) row_ptr[i] = s[t] - v + bofs[blockIdx.x];
}

__global__ __launch_bounds__(256) void fill_kernel(const int* __restrict__ src,
                                                   const int* __restrict__ dst,
                                                   int* __restrict__ cursor,
                                                   int* __restrict__ col, int E) {
    int e = blockIdx.x * 256 + threadIdx.x;
    if (e < E) {
        int p = atomicAdd(&cursor[dst[e]], 1);
        col[p] = src[e];
    }
}

// ================= f32 -> bf16 conversion (x once per call) =================
__global__ __launch_bounds__(256) void cvt_kernel(const float* __restrict__ x,
                                                  unsigned short* __restrict__ xb,
                                                  int n4) {
    int i = blockIdx.x * 256 + threadIdx.x;
    if (i < n4) {
        float4 v = reinterpret_cast<const float4*>(x)[i];
        uint2 o;
        o.x = (unsigned)f2bf(v.x) | ((unsigned)f2bf(v.y) << 16);
        o.y = (unsigned)f2bf(v.z) | ((unsigned)f2bf(v.w) << 16);
        reinterpret_cast<uint2*>(xb)[i] = o;
    }
}

// ================= gather-mean aggregation (bf16 in/out, f32 accum) =========
// one wave per dst node; lane l holds features [2l, 2l+1] (4B packed bf16x2).
// R8 counters: latency-bound (VALUBusy 22%, HBM 18%) — serial dependent
// gather chain. Fix: 4-wide manual unroll -> 4 independent row gathers in
// flight (MLP=4); beg/end readfirstlane'd so col[] loads compile to s_load.
__device__ __forceinline__ void bf2_acc(unsigned v, float& ax, float& ay) {
    ax += __uint_as_float(v << 16);
    ay += __uint_as_float(v & 0xFFFF0000u);
}

__global__ __launch_bounds__(256) void agg_kernel(const unsigned short* __restrict__ h,
                                                  const int* __restrict__ rp,
                                                  const int* __restrict__ col,
                                                  unsigned short* __restrict__ agg) {
    int w    = (blockIdx.x * 256 + threadIdx.x) >> 6;
    int lane = threadIdx.x & 63;
    if (w >= NN) return;
    int beg = __builtin_amdgcn_readfirstlane(rp[w]);
    int end = __builtin_amdgcn_readfirstlane(rp[w + 1]);
    const unsigned short* hl = h + lane * 2;
    float ax = 0.f, ay = 0.f;
    int e = beg;
    for (; e + 4 <= end; e += 4) {
        int s0 = col[e + 0], s1 = col[e + 1], s2 = col[e + 2], s3 = col[e + 3];
        unsigned v0 = *reinterpret_cast<const unsigned*>(hl + (size_t)s0 * FD);
        unsigned v1 = *reinterpret_cast<const unsigned*>(hl + (size_t)s1 * FD);
        unsigned v2 = *reinterpret_cast<const unsigned*>(hl + (size_t)s2 * FD);
        unsigned v3 = *reinterpret_cast<const unsigned*>(hl + (size_t)s3 * FD);
        bf2_acc(v0, ax, ay);
        bf2_acc(v1, ax, ay);
        bf2_acc(v2, ax, ay);
        bf2_acc(v3, ax, ay);
    }
    if (e + 2 <= end) {
        int s0 = col[e + 0], s1 = col[e + 1];
        unsigned v0 = *reinterpret_cast<const unsigned*>(hl + (size_t)s0 * FD);
        unsigned v1 = *reinterpret_cast<const unsigned*>(hl + (size_t)s1 * FD);
        bf2_acc(v0, ax, ay);
        bf2_acc(v1, ax, ay);
        e += 2;
    }
    if (e < end) {
        int s0 = col[e];
        unsigned v0 = *reinterpret_cast<const unsigned*>(hl + (size_t)s0 * FD);
        bf2_acc(v0, ax, ay);
    }
    float inv = 1.0f / fmaxf((float)(end - beg), 1.0f);
    ax *= inv;
    ay *= inv;
    *reinterpret_cast<unsigned*>(agg + (size_t)w * FD + lane * 2) =
        (unsigned)f2bf(ax) | ((unsigned)f2bf(ay) << 16);
}

// ================= MFMA SAGE GEMM =================
// out[n, jbase:jbase+64] = [h|agg](n,:) @ [Wself|Wneigh]^T + bias  (+ReLU)
// Tile 64 rows x 64 cols, K=256. 4 waves; wave w owns rows 16w..16w+15,
// 4 col-frags of 16. LDS A/B tiles [64][256] bf16, XOR-swizzled (T2):
// byte ^= (row&7)<<4 — row stride 512B would otherwise be a 32-way conflict.
// B staged from f32 weights with on-the-fly bf16 convert (weights L2-resident).
template <int NCOLS, bool RELU, bool OUTBF16>
__global__ __launch_bounds__(256) void mfma_gemm(const unsigned short* __restrict__ Ah,
                                                 const unsigned short* __restrict__ Ag,
                                                 const float* __restrict__ Wself,
                                                 const float* __restrict__ Wneigh,
                                                 const float* __restrict__ bias,
                                                 void* __restrict__ outp, int N) {
    __shared__ char lds[65536];                  // A: [0,32K) B: [32K,64K)
    char* Al = lds;
    char* Bl = lds + 32768;

    const int t     = threadIdx.x;
    const int n0    = blockIdx.x * 64;
    const int jbase = blockIdx.y * 64;

    // ---- stage A (h|agg rows) and B (weights, f32->bf16) ----
#pragma unroll
    for (int p = 0; p < 8; ++p) {
        int c    = t + p * 256;                  // chunk id 0..2047
        int row  = c >> 5;                       // 0..63
        int ch16 = c & 31;                       // 16B chunk within row
        int k8   = ch16 * 8;                     // k element base
        int n    = n0 + row;
        uint4 v  = make_uint4(0u, 0u, 0u, 0u);
        if (n < N) {
            const unsigned short* src = (k8 < 128)
                ? Ah + (size_t)n * FD + k8
                : Ag + (size_t)n * FD + (k8 - 128);
            v = *reinterpret_cast<const uint4*>(src);
        }
        *reinterpret_cast<uint4*>(Al + ((row * 512 + ch16 * 16) ^ ((row & 7) << 4))) = v;
    }
#pragma unroll
    for (int p = 0; p < 8; ++p) {
        int c    = t + p * 256;
        int row  = c >> 5;                       // output col within tile
        int ch16 = c & 31;
        int k8   = ch16 * 8;
        int j    = jbase + row;
        const float* src = (k8 < 128) ? (Wself + (size_t)j * 128 + k8)
                                      : (Wneigh + (size_t)j * 128 + (k8 - 128));
        float4 f0 = *reinterpret_cast<const float4*>(src);
        float4 f1 = *reinterpret_cast<const float4*>(src + 4);
        uint4 pk;
        pk.x = (unsigned)f2bf(f0.x) | ((unsigned)f2bf(f0.y) << 16);
        pk.y = (unsigned)f2bf(f0.z) | ((unsigned)f2bf(f0.w) << 16);
        pk.z = (unsigned)f2bf(f1.x) | ((unsigned)f2bf(f1.y) << 16);
        pk.w = (unsigned)f2bf(f1.z) | ((unsigned)f2bf(f1.w) << 16);
        *reinterpret_cast<uint4*>(Bl + ((row * 512 + ch16 * 16) ^ ((row & 7) << 4))) = pk;
    }
    __syncthreads();

    // ---- MFMA K-loop ----
    const int w   = t >> 6;
    const int l   = t & 63;
    const int lo4 = l & 15;
    const int hi  = l >> 4;
    const int xr  = (lo4 & 7) << 4;              // row&7 == lo4&7 for A and B

    f32x4 acc0 = {0.f, 0.f, 0.f, 0.f};
    f32x4 acc1 = {0.f, 0.f, 0.f, 0.f};
    f32x4 acc2 = {0.f, 0.f, 0.f, 0.f};
    f32x4 acc3 = {0.f, 0.f, 0.f, 0.f};

    const char* Arow = Al + (w * 16 + lo4) * 512;
#pragma unroll
    for (int ks = 0; ks < 8; ++ks) {
        int koff = (ks * 64 + hi * 16) ^ xr;
        bf16x8 a = *reinterpret_cast<const bf16x8*>(Arow + koff);
        bf16x8 b0 = *reinterpret_cast<const bf16x8*>(Bl + (0 * 16 + lo4) * 512 + koff);
        bf16x8 b1 = *reinterpret_cast<const bf16x8*>(Bl + (1 * 16 + lo4) * 512 + koff);
        bf16x8 b2 = *reinterpret_cast<const bf16x8*>(Bl + (2 * 16 + lo4) * 512 + koff);
        bf16x8 b3 = *reinterpret_cast<const bf16x8*>(Bl + (3 * 16 + lo4) * 512 + koff);
        acc0 = __builtin_amdgcn_mfma_f32_16x16x32_bf16(a, b0, acc0, 0, 0, 0);
        acc1 = __builtin_amdgcn_mfma_f32_16x16x32_bf16(a, b1, acc1, 0, 0, 0);
        acc2 = __builtin_amdgcn_mfma_f32_16x16x32_bf16(a, b2, acc2, 0, 0, 0);
        acc3 = __builtin_amdgcn_mfma_f32_16x16x32_bf16(a, b3, acc3, 0, 0, 0);
    }

    // ---- epilogue: bias (+ReLU); C/D map col=l&15, row=(l>>4)*4+reg (m89) ----
    unsigned short* hout = (unsigned short*)outp;
    float* fout = (float*)outp;
    const int rbase = n0 + w * 16 + hi * 4;
#pragma unroll
    for (int f = 0; f < 4; ++f) {
        f32x4 acc = (f == 0) ? acc0 : (f == 1) ? acc1 : (f == 2) ? acc2 : acc3;
        int col = jbase + f * 16 + lo4;
        float bv = bias[col];
#pragma unroll
        for (int r = 0; r < 4; ++r) {
            int n = rbase + r;
            if (n < N) {
                float v = acc[r] + bv;
                if (RELU) v = fmaxf(v, 0.f);
                if (OUTBF16) hout[(size_t)n * 128 + col] = f2bf(v);
                else         fout[(size_t)n * NCOLS + col] = v;
            }
        }
    }
}

extern "C" void kernel_launch(void* const* d_in, const int* in_sizes, int n_in,
                              void* d_out, int out_size, void* d_ws, size_t ws_size,
                              hipStream_t stream) {
    const float* x        = (const float*)d_in[0];
    const int*   edge_src = (const int*)d_in[1];
    const int*   edge_dst = (const int*)d_in[2];
    const float* Ws1 = (const float*)d_in[3];
    const float* Wn1 = (const float*)d_in[4];
    const float* b1  = (const float*)d_in[5];
    const float* Ws2 = (const float*)d_in[6];
    const float* Wn2 = (const float*)d_in[7];
    const float* b2  = (const float*)d_in[8];
    const float* Ws3 = (const float*)d_in[9];
    const float* Wn3 = (const float*)d_in[10];
    const float* b3  = (const float*)d_in[11];
    float* out = (float*)d_out;

    // ---- memory plan (d_ws == proven-safe 102.8 MB footprint) ----
    // d_ws : x_bf16 | h_a | h_b | agg (each NN*FD bf16 = 25.6MB) | cursor
    // d_out: col_src [NE] | row_ptr [NN+1] (CSR reads all precede final GEMM)
    // bsum aliases agg head (dead until first agg_kernel).
    unsigned short* x_bf = (unsigned short*)d_ws;
    unsigned short* h_a  = x_bf + (size_t)NN * FD;
    unsigned short* h_b  = h_a + (size_t)NN * FD;
    unsigned short* aggb = h_b + (size_t)NN * FD;
    int* cursor = (int*)(aggb + (size_t)NN * FD);
    int* bsum   = (int*)aggb;
    int* col_src = (int*)d_out;
    int* row_ptr = col_src + NE;

    const int edgeGrid = (NE + 255) / 256;
    const int aggGrid  = NN / 4;                         // 4 waves/block
    const int rowGrid  = (NN + 63) / 64;                 // 1563

    // ---- x -> bf16 ----
    cvt_kernel<<<(NN * FD / 4 + 255) / 256, 256, 0, stream>>>(x, x_bf, NN * FD / 4);

    // ---- CSR build ----
    hipMemsetAsync(cursor, 0, (size_t)NN * sizeof(int), stream);
    hist_kernel<<<edgeGrid, 256, 0, stream>>>(edge_dst, cursor, NE);
    scan_blocks<<<NB, 256, 0, stream>>>(cursor, bsum);
    scan_top<<<1, 512, 0, stream>>>(bsum, row_ptr);
    scan_write<<<NB, 256, 0, stream>>>(cursor, bsum, row_ptr);
    hipMemcpyAsync(cursor, row_ptr, (size_t)NN * sizeof(int),
                   hipMemcpyDeviceToDevice, stream);
    fill_kernel<<<edgeGrid, 256, 0, stream>>>(edge_src, edge_dst, cursor,
                                              col_src, NE);

    // ---- layer 1: x_bf -> h_a ----
    agg_kernel<<<aggGrid, 256, 0, stream>>>(x_bf, row_ptr, col_src, aggb);
    mfma_gemm<128, true, true><<<dim3(rowGrid, 2), 256, 0, stream>>>(
        x_bf, aggb, Ws1, Wn1, b1, h_a, NN);

    // ---- layer 2: h_a -> h_b ----
    agg_kernel<<<aggGrid, 256, 0, stream>>>(h_a, row_ptr, col_src, aggb);
    mfma_gemm<128, true, true><<<dim3(rowGrid, 2), 256, 0, stream>>>(
        h_a, aggb, Ws2, Wn2, b2, h_b, NN);

    // ---- layer 3: h_b -> out (f32, no ReLU; overwrites CSR in d_out) ----
    agg_kernel<<<aggGrid, 256, 0, stream>>>(h_b, row_ptr, col_src, aggb);
    mfma_gemm<64, false, false><<<dim3(rowGrid, 1), 256, 0, stream>>>(
        h_b, aggb, Ws3, Wn3, b3, out, NN);
}

// Round 11
// 359.639 us; speedup vs baseline: 9.6488x; 1.1116x over previous
//
#include <hip/hip_runtime.h>

#define NN 100000
#define NE 600000
#define FD 128                       // feature dim of h (in & hidden)
#define NB ((NN + 255) / 256)        // 391 scan blocks

typedef __attribute__((ext_vector_type(8))) short bf16x8;
typedef __attribute__((ext_vector_type(4))) float f32x4;

__device__ __forceinline__ unsigned short f2bf(float x) {
    unsigned int u = __float_as_uint(x);
    u += 0x7FFFu + ((u >> 16) & 1u);          // RNE
    return (unsigned short)(u >> 16);
}

// ================= CSR build (by destination) =================
__global__ __launch_bounds__(256) void hist_kernel(const int* __restrict__ dst,
                                                   int* __restrict__ cnt, int E) {
    int e = blockIdx.x * 256 + threadIdx.x;
    if (e < E) atomicAdd(&cnt[dst[e]], 1);
}

__global__ __launch_bounds__(256) void scan_blocks(const int* __restrict__ cnt,
                                                   int* __restrict__ bsum) {
    __shared__ int s[256];
    int i = blockIdx.x * 256 + threadIdx.x;
    int t = threadIdx.x;
    s[t] = (i < NN) ? cnt[i] : 0;
    __syncthreads();
    for (int off = 128; off > 0; off >>= 1) {
        if (t < off) s[t] += s[t + off];
        __syncthreads();
    }
    if (t == 0) bsum[blockIdx.x] = s[0];
}

__global__ __launch_bounds__(512) void scan_top(int* __restrict__ bsum,
                                                int* __restrict__ row_ptr) {
    __shared__ int s[512];
    int t = threadIdx.x;
    int v = (t < NB) ? bsum[t] : 0;
    s[t] = v;
    __syncthreads();
    for (int off = 1; off < 512; off <<= 1) {
        int x = (t >= off) ? s[t - off] : 0;
        __syncthreads();
        s[t] += x;
        __syncthreads();
    }
    if (t < NB) bsum[t] = s[t] - v;          // exclusive block offsets
    if (t == 0) row_ptr[NN] = NE;
}

__global__ __launch_bounds__(256) void scan_write(const int* __restrict__ cnt,
                                                  const int* __restrict__ bofs,
                                                  int* __restrict__ row_ptr) {
    __shared__ int s[256];
    int i = blockIdx.x * 256 + threadIdx.x;
    int t = threadIdx.x;
    int v = (i < NN) ? cnt[i] : 0;
    s[t] = v;
    __syncthreads();
    for (int off = 1; off < 256; off <<= 1) {
        int x = (t >= off) ? s[t - off] : 0;
        __syncthreads();
        s[t] += x;
        __syncthreads();
    }
    if (i < NN) row_ptr[i] = s[t] - v + bofs[blockIdx.x];
}

__global__ __launch_bounds__(256) void fill_kernel(const int* __restrict__ src,
                                                   const int* __restrict__ dst,
                                                   int* __restrict__ cursor,
                                                   int* __restrict__ col, int E) {
    int e = blockIdx.x * 256 + threadIdx.x;
    if (e < E) {
        int p = atomicAdd(&cursor[dst[e]], 1);
        col[p] = src[e];
    }
}

// ================= f32 -> bf16 conversion (x once per call) =================
__global__ __launch_bounds__(256) void cvt_kernel(const float* __restrict__ x,
                                                  unsigned short* __restrict__ xb,
                                                  int n4) {
    int i = blockIdx.x * 256 + threadIdx.x;
    if (i < n4) {
        float4 v = reinterpret_cast<const float4*>(x)[i];
        uint2 o;
        o.x = (unsigned)f2bf(v.x) | ((unsigned)f2bf(v.y) << 16);
        o.y = (unsigned)f2bf(v.z) | ((unsigned)f2bf(v.w) << 16);
        reinterpret_cast<uint2*>(xb)[i] = o;
    }
}

// ================= weight pre-convert: Wb[j][0:256] = bf16([Ws|Wn][j]) ======
// R10 PMC: every GEMM block re-converted the same f32 weights (VALU tax) and
// re-fetched them. Convert ONCE per layer into a packed bf16 [rows][256].
__global__ __launch_bounds__(256) void wcvt_kernel(const float* __restrict__ Ws,
                                                   const float* __restrict__ Wn,
                                                   unsigned short* __restrict__ Wb,
                                                   int rows) {
    int tid = blockIdx.x * 256 + threadIdx.x;
    if (tid >= rows * 64) return;
    int row = tid >> 6;
    int k   = (tid & 63) * 4;                 // chunk of 4, never straddles 128
    const float* src = (k < 128) ? (Ws + (size_t)row * 128 + k)
                                 : (Wn + (size_t)row * 128 + (k - 128));
    float4 v = *reinterpret_cast<const float4*>(src);
    uint2 o;
    o.x = (unsigned)f2bf(v.x) | ((unsigned)f2bf(v.y) << 16);
    o.y = (unsigned)f2bf(v.z) | ((unsigned)f2bf(v.w) << 16);
    *reinterpret_cast<uint2*>(Wb + (size_t)row * 256 + k) = o;
}

// ================= gather-mean aggregation (bf16 in/out, f32 accum) =========
// one wave per dst node; lane l holds features [2l, 2l+1] (4B packed bf16x2).
// 4-wide unroll -> 4 independent row gathers in flight (MLP=4): R8->R10
// measured 67.5 -> <52 us.
__device__ __forceinline__ void bf2_acc(unsigned v, float& ax, float& ay) {
    ax += __uint_as_float(v << 16);
    ay += __uint_as_float(v & 0xFFFF0000u);
}

__global__ __launch_bounds__(256) void agg_kernel(const unsigned short* __restrict__ h,
                                                  const int* __restrict__ rp,
                                                  const int* __restrict__ col,
                                                  unsigned short* __restrict__ agg) {
    int w    = (blockIdx.x * 256 + threadIdx.x) >> 6;
    int lane = threadIdx.x & 63;
    if (w >= NN) return;
    int beg = __builtin_amdgcn_readfirstlane(rp[w]);
    int end = __builtin_amdgcn_readfirstlane(rp[w + 1]);
    const unsigned short* hl = h + lane * 2;
    float ax = 0.f, ay = 0.f;
    int e = beg;
    for (; e + 4 <= end; e += 4) {
        int s0 = col[e + 0], s1 = col[e + 1], s2 = col[e + 2], s3 = col[e + 3];
        unsigned v0 = *reinterpret_cast<const unsigned*>(hl + (size_t)s0 * FD);
        unsigned v1 = *reinterpret_cast<const unsigned*>(hl + (size_t)s1 * FD);
        unsigned v2 = *reinterpret_cast<const unsigned*>(hl + (size_t)s2 * FD);
        unsigned v3 = *reinterpret_cast<const unsigned*>(hl + (size_t)s3 * FD);
        bf2_acc(v0, ax, ay);
        bf2_acc(v1, ax, ay);
        bf2_acc(v2, ax, ay);
        bf2_acc(v3, ax, ay);
    }
    if (e + 2 <= end) {
        int s0 = col[e + 0], s1 = col[e + 1];
        unsigned v0 = *reinterpret_cast<const unsigned*>(hl + (size_t)s0 * FD);
        unsigned v1 = *reinterpret_cast<const unsigned*>(hl + (size_t)s1 * FD);
        bf2_acc(v0, ax, ay);
        bf2_acc(v1, ax, ay);
        e += 2;
    }
    if (e < end) {
        int s0 = col[e];
        unsigned v0 = *reinterpret_cast<const unsigned*>(hl + (size_t)s0 * FD);
        bf2_acc(v0, ax, ay);
    }
    float inv = 1.0f / fmaxf((float)(end - beg), 1.0f);
    ax *= inv;
    ay *= inv;
    *reinterpret_cast<unsigned*>(agg + (size_t)w * FD + lane * 2) =
        (unsigned)f2bf(ax) | ((unsigned)f2bf(ay) << 16);
}

// ================= MFMA SAGE GEMM (v2) =================
// out[n, 0:BN] = [h|agg](n,:) @ Wb^T + bias  (+ReLU).  Full-width tile
// 64 rows x BN cols, K split into 2 chunks of 128 (A-chunk 0 = h, 1 = agg).
// LDS = 16KB A + BN*256B B = 48KB (BN=128) -> 3 blocks/CU (was 64KB -> 2):
// R10 showed Occupancy 17%, MfmaUtil 4% -> latency-bound staging.
// 4 waves; wave w rows 16w..16w+15; BN/16 col-frags; 64 MFMA/wave (BN=128).
// XOR swizzle byte ^= (row&7)<<4 on 256B-stride rows (write+read sides).
template <int BN, bool RELU, bool OUTBF16>
__global__ __launch_bounds__(256, 3) void mfma_gemm(const unsigned short* __restrict__ Ah,
                                                    const unsigned short* __restrict__ Ag,
                                                    const unsigned short* __restrict__ Wb,
                                                    const float* __restrict__ bias,
                                                    void* __restrict__ outp, int N) {
    __shared__ char lds[16384 + BN * 256];
    char* Al = lds;
    char* Bl = lds + 16384;

    const int t   = threadIdx.x;
    const int n0  = blockIdx.x * 64;
    const int w   = t >> 6;
    const int l   = t & 63;
    const int lo4 = l & 15;
    const int hi  = l >> 4;
    const int xr  = (lo4 & 7) << 4;

    f32x4 acc[BN / 16];
#pragma unroll
    for (int f = 0; f < BN / 16; ++f) acc[f] = {0.f, 0.f, 0.f, 0.f};

#pragma unroll
    for (int kc = 0; kc < 2; ++kc) {
        const unsigned short* Asrc = kc ? Ag : Ah;
        // ---- stage A chunk: 64 rows x 128 k = 16KB ----
#pragma unroll
        for (int p = 0; p < 4; ++p) {
            int c   = t + p * 256;               // 0..1023
            int row = c >> 4;
            int ch  = c & 15;
            int n   = n0 + row;
            uint4 v = make_uint4(0u, 0u, 0u, 0u);
            if (n < N) v = *reinterpret_cast<const uint4*>(Asrc + (size_t)n * FD + ch * 8);
            *reinterpret_cast<uint4*>(Al + ((row * 256 + ch * 16) ^ ((row & 7) << 4))) = v;
        }
        // ---- stage B chunk: BN rows x 128 k (bf16, pre-converted) ----
#pragma unroll
        for (int p = 0; p < BN / 16; ++p) {
            int c   = t + p * 256;               // 0..BN*16-1
            int row = c >> 4;
            int ch  = c & 15;
            uint4 v = *reinterpret_cast<const uint4*>(Wb + (size_t)row * 256 + kc * 128 + ch * 8);
            *reinterpret_cast<uint4*>(Bl + ((row * 256 + ch * 16) ^ ((row & 7) << 4))) = v;
        }
        __syncthreads();

        const char* Arow = Al + (w * 16 + lo4) * 256;
#pragma unroll
        for (int ks = 0; ks < 4; ++ks) {
            int koff = (ks * 64 + hi * 16) ^ xr;
            bf16x8 a = *reinterpret_cast<const bf16x8*>(Arow + koff);
#pragma unroll
            for (int f = 0; f < BN / 16; ++f) {
                bf16x8 b = *reinterpret_cast<const bf16x8*>(Bl + (f * 16 + lo4) * 256 + koff);
                acc[f] = __builtin_amdgcn_mfma_f32_16x16x32_bf16(a, b, acc[f], 0, 0, 0);
            }
        }
        __syncthreads();                          // next stage overwrites LDS
    }

    // ---- epilogue: bias (+ReLU); C/D map col=l&15, row=(l>>4)*4+reg (m89) ----
    unsigned short* hout = (unsigned short*)outp;
    float* fout = (float*)outp;
    const int rbase = n0 + w * 16 + hi * 4;
#pragma unroll
    for (int f = 0; f < BN / 16; ++f) {
        int col  = f * 16 + lo4;
        float bv = bias[col];
#pragma unroll
        for (int r = 0; r < 4; ++r) {
            int n = rbase + r;
            if (n < N) {
                float v = acc[f][r] + bv;
                if (RELU) v = fmaxf(v, 0.f);
                if (OUTBF16) hout[(size_t)n * 128 + col] = f2bf(v);
                else         fout[(size_t)n * BN + col] = v;
            }
        }
    }
}

extern "C" void kernel_launch(void* const* d_in, const int* in_sizes, int n_in,
                              void* d_out, int out_size, void* d_ws, size_t ws_size,
                              hipStream_t stream) {
    const float* x        = (const float*)d_in[0];
    const int*   edge_src = (const int*)d_in[1];
    const int*   edge_dst = (const int*)d_in[2];
    const float* Ws1 = (const float*)d_in[3];
    const float* Wn1 = (const float*)d_in[4];
    const float* b1  = (const float*)d_in[5];
    const float* Ws2 = (const float*)d_in[6];
    const float* Wn2 = (const float*)d_in[7];
    const float* b2  = (const float*)d_in[8];
    const float* Ws3 = (const float*)d_in[9];
    const float* Wn3 = (const float*)d_in[10];
    const float* b3  = (const float*)d_in[11];
    float* out = (float*)d_out;

    // ---- memory plan (d_ws == proven-safe 102.8 MB footprint) ----
    // d_ws : x_bf16 | h_a | h_b | agg (each NN*FD bf16 = 25.6MB) | cursor
    // d_out: col_src [NE] | row_ptr [NN+1] | pad | Wb1 | Wb2  (all reads
    //        complete before the final GEMM overwrites d_out)
    // Wb3 -> cursor region (dead after fill_kernel; wcvt3 runs after fill).
    // bsum aliases agg head (dead until first agg_kernel).
    unsigned short* x_bf = (unsigned short*)d_ws;
    unsigned short* h_a  = x_bf + (size_t)NN * FD;
    unsigned short* h_b  = h_a + (size_t)NN * FD;
    unsigned short* aggb = h_b + (size_t)NN * FD;
    int* cursor = (int*)(aggb + (size_t)NN * FD);
    int* bsum   = (int*)aggb;
    int* col_src = (int*)d_out;
    int* row_ptr = col_src + NE;
    unsigned short* wb1 = (unsigned short*)(col_src + NE + NN + 4);  // 16B-aligned
    unsigned short* wb2 = wb1 + 128 * 256;
    unsigned short* wb3 = (unsigned short*)cursor;                   // after fill

    const int edgeGrid = (NE + 255) / 256;
    const int aggGrid  = NN / 4;                         // 4 waves/block
    const int rowGrid  = (NN + 63) / 64;                 // 1563

    // ---- x -> bf16; weights -> packed bf16 ----
    cvt_kernel<<<(NN * FD / 4 + 255) / 256, 256, 0, stream>>>(x, x_bf, NN * FD / 4);
    wcvt_kernel<<<32, 256, 0, stream>>>(Ws1, Wn1, wb1, 128);
    wcvt_kernel<<<32, 256, 0, stream>>>(Ws2, Wn2, wb2, 128);

    // ---- CSR build ----
    hipMemsetAsync(cursor, 0, (size_t)NN * sizeof(int), stream);
    hist_kernel<<<edgeGrid, 256, 0, stream>>>(edge_dst, cursor, NE);
    scan_blocks<<<NB, 256, 0, stream>>>(cursor, bsum);
    scan_top<<<1, 512, 0, stream>>>(bsum, row_ptr);
    scan_write<<<NB, 256, 0, stream>>>(cursor, bsum, row_ptr);
    hipMemcpyAsync(cursor, row_ptr, (size_t)NN * sizeof(int),
                   hipMemcpyDeviceToDevice, stream);
    fill_kernel<<<edgeGrid, 256, 0, stream>>>(edge_src, edge_dst, cursor,
                                              col_src, NE);
    wcvt_kernel<<<16, 256, 0, stream>>>(Ws3, Wn3, wb3, 64);  // cursor now dead

    // ---- layer 1: x_bf -> h_a ----
    agg_kernel<<<aggGrid, 256, 0, stream>>>(x_bf, row_ptr, col_src, aggb);
    mfma_gemm<128, true, true><<<rowGrid, 256, 0, stream>>>(
        x_bf, aggb, wb1, b1, h_a, NN);

    // ---- layer 2: h_a -> h_b ----
    agg_kernel<<<aggGrid, 256, 0, stream>>>(h_a, row_ptr, col_src, aggb);
    mfma_gemm<128, true, true><<<rowGrid, 256, 0, stream>>>(
        h_a, aggb, wb2, b2, h_b, NN);

    // ---- layer 3: h_b -> out (f32, no ReLU; overwrites CSR+Wb in d_out) ----
    agg_kernel<<<aggGrid, 256, 0, stream>>>(h_b, row_ptr, col_src, aggb);
    mfma_gemm<64, false, false><<<rowGrid, 256, 0, stream>>>(
        h_b, aggb, wb3, b3, out, NN);
}